// Round 1
// baseline (7759.811 us; speedup 1.0000x reference)
//
#include <hip/hip_runtime.h>
#include <math.h>

// Problem constants (B=2, S=4096, H=2048, NH=16, NKV=4, HD=128)
constexpr int Bc   = 2;
constexpr int Sc   = 4096;
constexpr int Hc   = 2048;
constexpr int NHc  = 16;
constexpr int NKVc = 4;
constexpr int HDc  = 128;
constexpr int Gc   = 1024;   // group size = S * 0.25
constexpr int NGc  = 4;      // S / G
constexpr int HALFc = 512;   // G / 2

// ---------------------------------------------------------------------------
// Generic fp32 GEMM: C[M,N] = A[M,K] @ W[K,N], all row-major.
// 64x64 tile, K-tile 16, 256 threads, 4x4 micro-tile per thread.
// ---------------------------------------------------------------------------
__global__ __launch_bounds__(256) void gemm_f32(
    const float* __restrict__ A, const float* __restrict__ W,
    float* __restrict__ C, int M, int N, int K) {
  __shared__ float As[16][68];  // [k][m], pad to 68 for 16B-aligned rows
  __shared__ float Bs[16][68];  // [k][n]

  const int bm = blockIdx.y * 64;
  const int bn = blockIdx.x * 64;
  const int tid = threadIdx.x;
  const int trow = (tid >> 4) << 2;  // 0..60
  const int tcol = (tid & 15) << 2;  // 0..60

  float acc[4][4] = {};

  for (int k0 = 0; k0 < K; k0 += 16) {
    // Stage A tile: 64 rows x 16 k
    #pragma unroll
    for (int i = 0; i < 4; ++i) {
      int idx = tid + i * 256;         // 0..1023
      int r = idx >> 4, c = idx & 15;
      As[c][r] = A[(size_t)(bm + r) * K + (k0 + c)];
    }
    // Stage W tile: 16 k x 64 n
    #pragma unroll
    for (int i = 0; i < 4; ++i) {
      int idx = tid + i * 256;
      int kk = idx >> 6, n = idx & 63;
      Bs[kk][n] = W[(size_t)(k0 + kk) * N + (bn + n)];
    }
    __syncthreads();

    #pragma unroll
    for (int kk = 0; kk < 16; ++kk) {
      float4 a4 = *(const float4*)&As[kk][trow];
      float4 b4 = *(const float4*)&Bs[kk][tcol];
      float a[4] = {a4.x, a4.y, a4.z, a4.w};
      float b[4] = {b4.x, b4.y, b4.z, b4.w};
      #pragma unroll
      for (int i = 0; i < 4; ++i)
        #pragma unroll
        for (int j = 0; j < 4; ++j)
          acc[i][j] = fmaf(a[i], b[j], acc[i][j]);
    }
    __syncthreads();
  }

  #pragma unroll
  for (int i = 0; i < 4; ++i) {
    float4 v = make_float4(acc[i][0], acc[i][1], acc[i][2], acc[i][3]);
    *(float4*)&C[(size_t)(bm + trow + i) * N + (bn + tcol)] = v;
  }
}

// ---------------------------------------------------------------------------
// RoPE in-place on X laid out (B*S, nheads, HD). One thread per (bs, h, d<64).
// pair: x[d], x[d+64]; angle = pos * 10000^(-d/64)
// ---------------------------------------------------------------------------
__global__ __launch_bounds__(256) void rope_f32(
    float* __restrict__ X, const int* __restrict__ pos_ids, int nheads) {
  unsigned idx = blockIdx.x * 256 + threadIdx.x;
  int d = idx & 63;
  unsigned rest = idx >> 6;
  int h = rest % nheads;
  unsigned bs = rest / nheads;

  float t = (float)pos_ids[bs];
  float inv_freq = powf(10000.0f, -(float)d * (1.0f / 64.0f));
  float ang = t * inv_freq;
  float cs, sn;
  sincosf(ang, &sn, &cs);

  float* p = X + ((size_t)bs * nheads + h) * HDc;
  float x0 = p[d];
  float x1 = p[d + 64];
  p[d]      = x0 * cs - x1 * sn;
  p[d + 64] = x1 * cs + x0 * sn;
}

// ---------------------------------------------------------------------------
// Grouped causal attention with S2-shift indexing, online softmax.
// One wave (64 lanes) per query row; each lane owns 2 of the 128 head dims.
// Q: (B,S,NH,HD), K/V: (B,S,NKV,HD); output O: (B,S,NH,HD) at un-shifted pos.
// wave id bits: r[0:10) | h[10:14) | bg[14:17)
// ---------------------------------------------------------------------------
__global__ __launch_bounds__(256) void attn_f32(
    const float* __restrict__ Q, const float* __restrict__ K,
    const float* __restrict__ V, float* __restrict__ O) {
  const int wave = (blockIdx.x << 2) + (threadIdx.x >> 6);
  const int lane = threadIdx.x & 63;

  const int r  = wave & (Gc - 1);
  const int h  = (wave >> 10) & (NHc - 1);
  const int bg = wave >> 14;           // 0..B*NG-1
  const int b  = bg >> 2;              // NG = 4
  const int gi = bg & 3;

  const int shift  = (h >= NHc / 2) ? HALFc : 0;
  const int base_s = gi * Gc;
  const int sq = (base_s + r + shift) & (Sc - 1);
  const int kvh = h >> 2;              // n_rep = 4

  const float2 q = ((const float2*)(Q + (((size_t)(b * Sc + sq)) * NHc + h) * HDc))[lane];

  float m = -1e30f, l = 0.0f;
  float ox = 0.0f, oy = 0.0f;
  const float scale = 0.08838834764831845f;  // 1/sqrt(128)

  for (int k = 0; k <= r; ++k) {
    const int sk = (base_s + k + shift) & (Sc - 1);
    const size_t kvbase = (((size_t)(b * Sc + sk)) * NKVc + kvh) * HDc;
    const float2 kv = ((const float2*)(K + kvbase))[lane];
    const float2 vv = ((const float2*)(V + kvbase))[lane];

    float part = q.x * kv.x + q.y * kv.y;
    #pragma unroll
    for (int off = 32; off; off >>= 1) part += __shfl_xor(part, off, 64);

    const float score = part * scale;
    const float newm = fmaxf(m, score);
    const float corr = __expf(m - newm);
    const float p = __expf(score - newm);
    ox = ox * corr + p * vv.x;
    oy = oy * corr + p * vv.y;
    l = l * corr + p;
    m = newm;
  }

  const float inv = 1.0f / l;
  // un-shift: output lands back at seq position sq for all heads
  ((float2*)(O + (((size_t)(b * Sc + sq)) * NHc + h) * HDc))[lane] =
      make_float2(ox * inv, oy * inv);
}

// ---------------------------------------------------------------------------
extern "C" void kernel_launch(void* const* d_in, const int* in_sizes, int n_in,
                              void* d_out, int out_size, void* d_ws, size_t ws_size,
                              hipStream_t stream) {
  const float* hs  = (const float*)d_in[0];
  // d_in[1] = attention_mask (pure causal per group -> handled by loop bound)
  const int*   pos = (const int*)d_in[2];
  const float* Wq  = (const float*)d_in[3];
  const float* Wk  = (const float*)d_in[4];
  const float* Wv  = (const float*)d_in[5];
  const float* Wo  = (const float*)d_in[6];
  float* out = (float*)d_out;

  // Workspace layout (floats): Q | K | V | AttnOut
  float* Qb = (float*)d_ws;
  float* Kb = Qb + (size_t)Bc * Sc * NHc * HDc;    // +16,777,216
  float* Vb = Kb + (size_t)Bc * Sc * NKVc * HDc;   // + 4,194,304
  float* Ob = Vb + (size_t)Bc * Sc * NKVc * HDc;   // + 4,194,304

  const int M = Bc * Sc;  // 8192
  dim3 blk(256);

  // Projections
  gemm_f32<<<dim3(Hc / 64, M / 64), blk, 0, stream>>>(hs, Wq, Qb, M, Hc, Hc);
  gemm_f32<<<dim3((NKVc * HDc) / 64, M / 64), blk, 0, stream>>>(hs, Wk, Kb, M, NKVc * HDc, Hc);
  gemm_f32<<<dim3((NKVc * HDc) / 64, M / 64), blk, 0, stream>>>(hs, Wv, Vb, M, NKVc * HDc, Hc);

  // RoPE on Q and K
  rope_f32<<<(Bc * Sc * NHc * 64) / 256, blk, 0, stream>>>(Qb, pos, NHc);
  rope_f32<<<(Bc * Sc * NKVc * 64) / 256, blk, 0, stream>>>(Kb, pos, NKVc);

  // Grouped causal attention with S2 shift (writes un-shifted layout)
  attn_f32<<<(Bc * NGc * NHc * Gc) / 4, blk, 0, stream>>>(Qb, Kb, Vb, Ob);

  // Output projection
  gemm_f32<<<dim3(Hc / 64, M / 64), blk, 0, stream>>>(Ob, Wo, out, M, Hc, Hc);
}

// Round 2
// 4674.986 us; speedup vs baseline: 1.6599x; 1.6599x over previous
//
#include <hip/hip_runtime.h>
#include <hip/hip_bf16.h>
#include <math.h>

// Problem constants (B=2, S=4096, H=2048, NH=16, NKV=4, HD=128)
constexpr int Bc   = 2;
constexpr int Sc   = 4096;
constexpr int Hc   = 2048;
constexpr int NHc  = 16;
constexpr int NKVc = 4;
constexpr int HDc  = 128;
constexpr int Gc   = 1024;   // group size = S * 0.25
constexpr int NGc  = 4;      // S / G
constexpr int HALFc = 512;   // G / 2

// ---------------------------------------------------------------------------
// Generic fp32 GEMM: C[M,N] = A[M,K] @ W[K,N], all row-major.
// 64x64 tile, K-tile 16, 256 threads, 4x4 micro-tile per thread.
// ---------------------------------------------------------------------------
__global__ __launch_bounds__(256) void gemm_f32(
    const float* __restrict__ A, const float* __restrict__ W,
    float* __restrict__ C, int M, int N, int K) {
  __shared__ float As[16][68];
  __shared__ float Bs[16][68];

  const int bm = blockIdx.y * 64;
  const int bn = blockIdx.x * 64;
  const int tid = threadIdx.x;
  const int trow = (tid >> 4) << 2;
  const int tcol = (tid & 15) << 2;

  float acc[4][4] = {};

  for (int k0 = 0; k0 < K; k0 += 16) {
    #pragma unroll
    for (int i = 0; i < 4; ++i) {
      int idx = tid + i * 256;
      int r = idx >> 4, c = idx & 15;
      As[c][r] = A[(size_t)(bm + r) * K + (k0 + c)];
    }
    #pragma unroll
    for (int i = 0; i < 4; ++i) {
      int idx = tid + i * 256;
      int kk = idx >> 6, n = idx & 63;
      Bs[kk][n] = W[(size_t)(k0 + kk) * N + (bn + n)];
    }
    __syncthreads();

    #pragma unroll
    for (int kk = 0; kk < 16; ++kk) {
      float4 a4 = *(const float4*)&As[kk][trow];
      float4 b4 = *(const float4*)&Bs[kk][tcol];
      float a[4] = {a4.x, a4.y, a4.z, a4.w};
      float b[4] = {b4.x, b4.y, b4.z, b4.w};
      #pragma unroll
      for (int i = 0; i < 4; ++i)
        #pragma unroll
        for (int j = 0; j < 4; ++j)
          acc[i][j] = fmaf(a[i], b[j], acc[i][j]);
    }
    __syncthreads();
  }

  #pragma unroll
  for (int i = 0; i < 4; ++i) {
    float4 v = make_float4(acc[i][0], acc[i][1], acc[i][2], acc[i][3]);
    *(float4*)&C[(size_t)(bm + trow + i) * N + (bn + tcol)] = v;
  }
}

// ---------------------------------------------------------------------------
// RoPE in-place on X laid out (B*S, nheads, HD).
// ---------------------------------------------------------------------------
__global__ __launch_bounds__(256) void rope_f32(
    float* __restrict__ X, const int* __restrict__ pos_ids, int nheads) {
  unsigned idx = blockIdx.x * 256 + threadIdx.x;
  int d = idx & 63;
  unsigned rest = idx >> 6;
  int h = rest % nheads;
  unsigned bs = rest / nheads;

  float t = (float)pos_ids[bs];
  float inv_freq = powf(10000.0f, -(float)d * (1.0f / 64.0f));
  float ang = t * inv_freq;
  float cs, sn;
  sincosf(ang, &sn, &cs);

  float* p = X + ((size_t)bs * nheads + h) * HDc;
  float x0 = p[d];
  float x1 = p[d + 64];
  p[d]      = x0 * cs - x1 * sn;
  p[d + 64] = x1 * cs + x0 * sn;
}

// ---------------------------------------------------------------------------
// Tiled flash attention with S2-shift indexing.
// Block: 256 threads = (tx 0..15) x (ty 0..15); one 64-query tile of one
// (b, group, head). Keys iterated in 64-wide tiles; K/V staged to LDS in two
// 64-dim halves sharing one buffer. P kept in bf16 LDS.
// Thread (ty,tx): S rows {ty+16i}, S cols {tx+16j};
//                 O rows {ty+16i}, O cols {4tx..4tx+3, 64+4tx..64+4tx+3}.
// ---------------------------------------------------------------------------
__global__ __launch_bounds__(256) void attn_flash(
    const float* __restrict__ Q, const float* __restrict__ K,
    const float* __restrict__ V, float* __restrict__ O) {
  __shared__ float Qs[64 * 132];            // 33792 B (pad 132: 16B-aligned rows)
  __shared__ float KVs[64 * 68];            // 17408 B (shared K-half / V-half)
  __shared__ __hip_bfloat16 Ps[64 * 72];    //  9216 B

  const int bid = blockIdx.x;
  const int qt = 15 - (bid & 15);           // big-work blocks first
  const int h  = (bid >> 4) & 15;
  const int gi = (bid >> 8) & 3;
  const int b  = bid >> 10;

  const int tid = threadIdx.x;
  const int tx = tid & 15, ty = tid >> 4;

  const int shift = (h >= NHc / 2) ? HALFc : 0;
  const int base_s = gi * Gc;
  const int kvh = h >> 2;                   // n_rep = 4

  // ---- stage Q tile: rows qt*64 .. qt*64+63 ----
  {
    const int row = tid >> 2;               // 0..63
    const int d0  = (tid & 3) * 32;
    const int r = qt * 64 + row;
    const int sq = (base_s + r + shift) & (Sc - 1);
    const float* src = Q + (((size_t)(b * Sc + sq)) * NHc + h) * HDc + d0;
    #pragma unroll
    for (int u = 0; u < 8; ++u)
      *(float4*)&Qs[row * 132 + d0 + 4 * u] = *(const float4*)&src[4 * u];
  }

  float o[4][8];
  float m[4], l[4];
  #pragma unroll
  for (int i = 0; i < 4; ++i) {
    m[i] = -1e30f; l[i] = 0.0f;
    #pragma unroll
    for (int c = 0; c < 8; ++c) o[i][c] = 0.0f;
  }

  const int krow = tid >> 2;                // K/V staging: row per 4 threads
  const int kd0  = (tid & 3) * 16;          // 16 floats each (one 64-d half)
  const float scale = 0.08838834764831845f; // 1/sqrt(128)

  for (int kt = 0; kt <= qt; ++kt) {
    const int sk_row = (base_s + kt * 64 + krow + shift) & (Sc - 1);
    const size_t kvbase = (((size_t)(b * Sc + sk_row)) * NKVc + kvh) * HDc + kd0;

    float s[4][4] = {};

    // ---- S = Q K^T over two 64-dim halves ----
    #pragma unroll
    for (int half = 0; half < 2; ++half) {
      __syncthreads();                      // KVs free (prev reader done)
      {
        const float* src = K + kvbase + half * 64;
        #pragma unroll
        for (int u = 0; u < 4; ++u)
          *(float4*)&KVs[krow * 68 + kd0 + 4 * u] = *(const float4*)&src[4 * u];
      }
      __syncthreads();                      // K half staged

      for (int dl = 0; dl < 64; dl += 4) {
        const int dg = half * 64 + dl;
        float4 a4[4], b4[4];
        #pragma unroll
        for (int i = 0; i < 4; ++i) a4[i] = *(const float4*)&Qs[(ty + 16 * i) * 132 + dg];
        #pragma unroll
        for (int j = 0; j < 4; ++j) b4[j] = *(const float4*)&KVs[(tx + 16 * j) * 68 + dl];
        #pragma unroll
        for (int i = 0; i < 4; ++i)
          #pragma unroll
          for (int j = 0; j < 4; ++j) {
            s[i][j] = fmaf(a4[i].x, b4[j].x, s[i][j]);
            s[i][j] = fmaf(a4[i].y, b4[j].y, s[i][j]);
            s[i][j] = fmaf(a4[i].z, b4[j].z, s[i][j]);
            s[i][j] = fmaf(a4[i].w, b4[j].w, s[i][j]);
          }
      }
    }

    // ---- online softmax (per row, reduce across the 16 tx lanes) ----
    float corr[4];
    #pragma unroll
    for (int i = 0; i < 4; ++i) {
      #pragma unroll
      for (int j = 0; j < 4; ++j) {
        s[i][j] *= scale;
        if (kt == qt && (tx + 16 * j) > (ty + 16 * i)) s[i][j] = -1e30f;
      }
      float mx = fmaxf(fmaxf(s[i][0], s[i][1]), fmaxf(s[i][2], s[i][3]));
      #pragma unroll
      for (int off = 1; off < 16; off <<= 1) mx = fmaxf(mx, __shfl_xor(mx, off, 64));
      const float mnew = fmaxf(m[i], mx);
      corr[i] = __expf(m[i] - mnew);
      float sum = 0.0f;
      #pragma unroll
      for (int j = 0; j < 4; ++j) {
        const float p = __expf(s[i][j] - mnew);
        s[i][j] = p;
        sum += p;
      }
      #pragma unroll
      for (int off = 1; off < 16; off <<= 1) sum += __shfl_xor(sum, off, 64);
      l[i] = l[i] * corr[i] + sum;
      m[i] = mnew;
    }

    __syncthreads();                        // S done reading KVs (K-h1)

    // write P (bf16) and stage V half 0
    #pragma unroll
    for (int i = 0; i < 4; ++i)
      #pragma unroll
      for (int j = 0; j < 4; ++j)
        Ps[(ty + 16 * i) * 72 + tx + 16 * j] = __float2bfloat16(s[i][j]);
    {
      const float* src = V + kvbase;        // half 0
      #pragma unroll
      for (int u = 0; u < 4; ++u)
        *(float4*)&KVs[krow * 68 + kd0 + 4 * u] = *(const float4*)&src[4 * u];
    }
    __syncthreads();                        // P + V-h0 visible

    // rescale O by corr (once per tile)
    #pragma unroll
    for (int i = 0; i < 4; ++i)
      #pragma unroll
      for (int c = 0; c < 8; ++c) o[i][c] *= corr[i];

    // ---- PV half 0: O cols 4tx..4tx+3 ----
    for (int kk = 0; kk < 64; ++kk) {
      float4 v4 = *(const float4*)&KVs[kk * 68 + 4 * tx];
      #pragma unroll
      for (int i = 0; i < 4; ++i) {
        const float p = __bfloat162float(Ps[(ty + 16 * i) * 72 + kk]);
        o[i][0] = fmaf(p, v4.x, o[i][0]);
        o[i][1] = fmaf(p, v4.y, o[i][1]);
        o[i][2] = fmaf(p, v4.z, o[i][2]);
        o[i][3] = fmaf(p, v4.w, o[i][3]);
      }
    }

    __syncthreads();                        // PV-h0 done with KVs
    {
      const float* src = V + kvbase + 64;   // half 1
      #pragma unroll
      for (int u = 0; u < 4; ++u)
        *(float4*)&KVs[krow * 68 + kd0 + 4 * u] = *(const float4*)&src[4 * u];
    }
    __syncthreads();                        // V-h1 staged

    // ---- PV half 1: O cols 64+4tx..64+4tx+3 ----
    for (int kk = 0; kk < 64; ++kk) {
      float4 v4 = *(const float4*)&KVs[kk * 68 + 4 * tx];
      #pragma unroll
      for (int i = 0; i < 4; ++i) {
        const float p = __bfloat162float(Ps[(ty + 16 * i) * 72 + kk]);
        o[i][4] = fmaf(p, v4.x, o[i][4]);
        o[i][5] = fmaf(p, v4.y, o[i][5]);
        o[i][6] = fmaf(p, v4.z, o[i][6]);
        o[i][7] = fmaf(p, v4.w, o[i][7]);
      }
    }
  }

  // ---- normalize and store (un-shift: output lands at seq position sq) ----
  #pragma unroll
  for (int i = 0; i < 4; ++i) {
    const float inv = 1.0f / l[i];
    const int r = qt * 64 + ty + 16 * i;
    const int sq = (base_s + r + shift) & (Sc - 1);
    float* dst = O + (((size_t)(b * Sc + sq)) * NHc + h) * HDc;
    float4 w0 = make_float4(o[i][0] * inv, o[i][1] * inv, o[i][2] * inv, o[i][3] * inv);
    float4 w1 = make_float4(o[i][4] * inv, o[i][5] * inv, o[i][6] * inv, o[i][7] * inv);
    *(float4*)&dst[4 * tx] = w0;
    *(float4*)&dst[64 + 4 * tx] = w1;
  }
}

// ---------------------------------------------------------------------------
extern "C" void kernel_launch(void* const* d_in, const int* in_sizes, int n_in,
                              void* d_out, int out_size, void* d_ws, size_t ws_size,
                              hipStream_t stream) {
  const float* hs  = (const float*)d_in[0];
  const int*   pos = (const int*)d_in[2];
  const float* Wq  = (const float*)d_in[3];
  const float* Wk  = (const float*)d_in[4];
  const float* Wv  = (const float*)d_in[5];
  const float* Wo  = (const float*)d_in[6];
  float* out = (float*)d_out;

  float* Qb = (float*)d_ws;
  float* Kb = Qb + (size_t)Bc * Sc * NHc * HDc;
  float* Vb = Kb + (size_t)Bc * Sc * NKVc * HDc;
  float* Ob = Vb + (size_t)Bc * Sc * NKVc * HDc;

  const int M = Bc * Sc;  // 8192
  dim3 blk(256);

  gemm_f32<<<dim3(Hc / 64, M / 64), blk, 0, stream>>>(hs, Wq, Qb, M, Hc, Hc);
  gemm_f32<<<dim3((NKVc * HDc) / 64, M / 64), blk, 0, stream>>>(hs, Wk, Kb, M, NKVc * HDc, Hc);
  gemm_f32<<<dim3((NKVc * HDc) / 64, M / 64), blk, 0, stream>>>(hs, Wv, Vb, M, NKVc * HDc, Hc);

  rope_f32<<<(Bc * Sc * NHc * 64) / 256, blk, 0, stream>>>(Qb, pos, NHc);
  rope_f32<<<(Bc * Sc * NKVc * 64) / 256, blk, 0, stream>>>(Kb, pos, NKVc);

  // flash attention: B*NG*NH*(G/64) = 2048 blocks
  attn_flash<<<Bc * NGc * NHc * (Gc / 64), blk, 0, stream>>>(Qb, Kb, Vb, Ob);

  gemm_f32<<<dim3(Hc / 64, M / 64), blk, 0, stream>>>(Ob, Wo, out, M, Hc, Hc);
}

// Round 3
// 695.552 us; speedup vs baseline: 11.1563x; 6.7213x over previous
//
#include <hip/hip_runtime.h>
#include <math.h>

typedef unsigned short u16;
typedef short bf16x8 __attribute__((ext_vector_type(8)));
typedef float f32x4 __attribute__((ext_vector_type(4)));

// Problem constants (B=2, S=4096, H=2048, NH=16, NKV=4, HD=128, g=1024)

__device__ __forceinline__ u16 f2bf(float x) {
  union { float f; unsigned u; } c; c.f = x;
  unsigned r = (c.u + 0x7FFFu + ((c.u >> 16) & 1u)) >> 16;  // RNE
  return (u16)r;
}
__device__ __forceinline__ float bf2f(u16 x) {
  union { unsigned u; float f; } c; c.u = ((unsigned)x) << 16;
  return c.f;
}

// async 16B global -> LDS (wave-uniform base + lane*16 on the LDS side)
#define GLD16(gp, lp)                                                   \
  __builtin_amdgcn_global_load_lds(                                     \
      (__attribute__((address_space(1))) void*)(gp),                    \
      (__attribute__((address_space(3))) void*)(lp), 16, 0, 0)

// ---------------------------------------------------------------------------
// fp32 -> bf16 elementwise cast (hidden_states)
// ---------------------------------------------------------------------------
__global__ __launch_bounds__(256) void cast_bf16_vec(
    const float* __restrict__ X, u16* __restrict__ Y) {
  const size_t i = ((size_t)blockIdx.x * 256 + threadIdx.x) * 4;
  float4 v = *(const float4*)(X + i);
  ushort4 o;
  o.x = f2bf(v.x); o.y = f2bf(v.y); o.z = f2bf(v.z); o.w = f2bf(v.w);
  *(ushort4*)(Y + i) = o;
}

// ---------------------------------------------------------------------------
// W (K x N fp32, row-major) -> Wt (N x K bf16, row-major). 64x64 LDS tiles.
// ---------------------------------------------------------------------------
__global__ __launch_bounds__(256) void wt_cast(
    const float* __restrict__ W, u16* __restrict__ Wt, int K, int N) {
  const int bk = blockIdx.y * 64;
  const int bn = blockIdx.x * 64;
  __shared__ float T[64 * 65];
  const int tid = threadIdx.x;
  #pragma unroll
  for (int u = 0; u < 16; ++u) {
    int idx = tid + u * 256;
    int kl = idx >> 6, nl = idx & 63;
    T[kl * 65 + nl] = W[(size_t)(bk + kl) * N + bn + nl];
  }
  __syncthreads();
  #pragma unroll
  for (int u = 0; u < 16; ++u) {
    int idx = tid + u * 256;
    int nl = idx >> 6, kl = idx & 63;
    Wt[(size_t)(bn + nl) * K + bk + kl] = f2bf(T[kl * 65 + nl]);
  }
}

// ---------------------------------------------------------------------------
// bf16 MFMA GEMM (m97 structure): C[M,N] = A[M,K] @ Bt[N,K]^T
// 128x128 tile, BK=32, 256 thr / 4 waves, each wave 64x64 via 4x4 16x16x32.
// Output: fp32 (Cf) or bf16 (Cb) - exactly one non-null.
// ---------------------------------------------------------------------------
__global__ __launch_bounds__(256) void gemm_bf16(
    const u16* __restrict__ A, const u16* __restrict__ Bt,
    float* __restrict__ Cf, u16* __restrict__ Cb, int M, int N, int K) {
  __shared__ u16 As[128 * 32];
  __shared__ u16 Bs[128 * 32];

  const int tid = threadIdx.x;
  const int bm = blockIdx.y * 128;
  const int bn = blockIdx.x * 128;
  const int w = tid >> 6, lane = tid & 63;
  const int col = lane & 15, quad = lane >> 4;
  const int mblk = (w & 1) * 64, nblk = (w >> 1) * 64;

  const int srow = tid >> 2;          // 0..63
  const int sseg = (tid & 3) * 8;     // 8 bf16 = 16 B

  const u16* ag0 = A + (size_t)(bm + srow) * K + sseg;
  const u16* ag1 = A + (size_t)(bm + 64 + srow) * K + sseg;
  const u16* bg0 = Bt + (size_t)(bn + srow) * K + sseg;
  const u16* bg1 = Bt + (size_t)(bn + 64 + srow) * K + sseg;
  u16* al = &As[srow * 32 + sseg];    // == tid*16 bytes (wave-contiguous)
  u16* bl = &Bs[srow * 32 + sseg];

  f32x4 acc[4][4];
  #pragma unroll
  for (int i = 0; i < 4; ++i)
    #pragma unroll
    for (int j = 0; j < 4; ++j) acc[i][j] = (f32x4)(0.0f);

  for (int k0 = 0; k0 < K; k0 += 32) {
    __syncthreads();
    GLD16(ag0 + k0, al);
    GLD16(ag1 + k0, al + 64 * 32);
    GLD16(bg0 + k0, bl);
    GLD16(bg1 + k0, bl + 64 * 32);
    __syncthreads();

    bf16x8 af[4], bfr[4];
    #pragma unroll
    for (int i = 0; i < 4; ++i)
      af[i] = *(const bf16x8*)&As[(mblk + 16 * i + col) * 32 + quad * 8];
    #pragma unroll
    for (int j = 0; j < 4; ++j)
      bfr[j] = *(const bf16x8*)&Bs[(nblk + 16 * j + col) * 32 + quad * 8];
    #pragma unroll
    for (int i = 0; i < 4; ++i)
      #pragma unroll
      for (int j = 0; j < 4; ++j)
        acc[i][j] = __builtin_amdgcn_mfma_f32_16x16x32_bf16(af[i], bfr[j], acc[i][j], 0, 0, 0);
  }

  // C/D layout: col = lane&15, row = quad*4 + reg  [verified m89/m91]
  #pragma unroll
  for (int i = 0; i < 4; ++i) {
    const int row0 = bm + mblk + 16 * i + quad * 4;
    #pragma unroll
    for (int j = 0; j < 4; ++j) {
      const int cc = bn + nblk + 16 * j + col;
      #pragma unroll
      for (int r = 0; r < 4; ++r) {
        if (Cb) Cb[(size_t)(row0 + r) * N + cc] = f2bf(acc[i][j][r]);
        else    Cf[(size_t)(row0 + r) * N + cc] = acc[i][j][r];
      }
    }
  }
}

// ---------------------------------------------------------------------------
// RoPE in-place on bf16 X laid out (B*S, nh*128). One thread per (bs,h,d<64).
// ---------------------------------------------------------------------------
__global__ __launch_bounds__(256) void rope_bf16(
    u16* __restrict__ X, const int* __restrict__ pos, int nh) {
  const unsigned idx = blockIdx.x * 256 + threadIdx.x;
  const int d = idx & 63;
  const unsigned rest = idx >> 6;
  const int hh = rest % nh;
  const unsigned bs = rest / nh;

  u16* p = X + (size_t)bs * (nh * 128) + hh * 128 + d;
  const float x0 = bf2f(p[0]);
  const float x1 = bf2f(p[64]);
  const float t = (float)pos[bs];
  const float inv_freq = expf((float)d * -0.14391156509676332f);  // ln(1e4)/64
  float s, c;
  sincosf(t * inv_freq, &s, &c);
  p[0]  = f2bf(x0 * c - x1 * s);
  p[64] = f2bf(x1 * c + x0 * s);
}

// ---------------------------------------------------------------------------
// V (B*S, NKV*128) bf16 -> Vt (B, NKV, 128, S) bf16 (key-contiguous rows)
// ---------------------------------------------------------------------------
__global__ __launch_bounds__(256) void v_transpose(
    const u16* __restrict__ Vb, u16* __restrict__ Vt) {
  const int bid = blockIdx.x;
  const int st = bid & 63;
  const int kvh = (bid >> 6) & 3;
  const int b = bid >> 8;
  __shared__ u16 T[64 * 136];
  const int tid = threadIdx.x;
  #pragma unroll
  for (int u = 0; u < 4; ++u) {
    int idx = tid + u * 256;
    int sl = idx >> 4, ch = idx & 15;
    *(uint4*)&T[sl * 136 + ch * 8] =
        *(const uint4*)(Vb + ((size_t)(b * 4096 + st * 64 + sl)) * 512 + kvh * 128 + ch * 8);
  }
  __syncthreads();
  #pragma unroll
  for (int u = 0; u < 32; ++u) {
    int idx = tid + u * 256;
    int d = idx >> 6, sl = idx & 63;
    Vt[((size_t)((b * 4 + kvh) * 128 + d)) * 4096 + st * 64 + sl] = T[sl * 136 + d];
  }
}

// ---------------------------------------------------------------------------
// MFMA flash attention with S2-shift indexing.
// Block = 256 thr / 4 waves; 64-query tile of one (b,group,head); 64-key tiles.
// Wave w owns q-rows w*16..w*16+15. All LDS rows padded to 17x16B (conflict-free).
// ---------------------------------------------------------------------------
__global__ __launch_bounds__(256) void attn_mfma(
    const u16* __restrict__ Qb, const u16* __restrict__ Kb,
    const u16* __restrict__ Vt, u16* __restrict__ Ob) {
  __shared__ u16 Qs[64 * 136];    // [q][128d], row 272 B
  __shared__ u16 Ks[64 * 136];    // [key][128d]
  __shared__ u16 Vs[128 * 72];    // [dim][64key], row 144 B
  __shared__ u16 Ps[4][16 * 72];  // per-wave P [16q][64key]

  const int bid = blockIdx.x;
  const int qt = 15 - (bid & 15);           // heavy tiles first
  const int h  = (bid >> 4) & 15;
  const int gi = (bid >> 8) & 3;
  const int b  = bid >> 10;

  const int tid = threadIdx.x;
  const int w = tid >> 6, lane = tid & 63;
  const int col = lane & 15, quad = lane >> 4;

  const int shift = (h >= 8) ? 512 : 0;
  const int base_s = gi * 1024;
  const int kvh = h >> 2;

  // ---- stage Q tile (64 contiguous shifted seq rows) ----
  const int sq0 = (base_s + qt * 64 + shift) & 4095;
  {
    const u16* qsrc = Qb + ((size_t)(b * 4096 + sq0)) * 2048 + h * 128;
    #pragma unroll
    for (int u = 0; u < 4; ++u) {
      int idx = tid + u * 256;
      int row = idx >> 4, ch = idx & 15;
      *(uint4*)&Qs[row * 136 + ch * 8] =
          *(const uint4*)(qsrc + (size_t)row * 2048 + ch * 8);
    }
  }
  __syncthreads();

  // A-frags of Q (persist across K-tiles): A[m=lane&15][k=quad*8+j]
  bf16x8 aq[4];
  #pragma unroll
  for (int kk = 0; kk < 4; ++kk)
    aq[kk] = *(const bf16x8*)&Qs[(w * 16 + col) * 136 + kk * 32 + quad * 8];

  f32x4 o[8];
  #pragma unroll
  for (int jd = 0; jd < 8; ++jd) o[jd] = (f32x4)(0.0f);
  float mr[4], lr[4];
  #pragma unroll
  for (int r = 0; r < 4; ++r) { mr[r] = -1e30f; lr[r] = 0.0f; }

  const float scale = 0.08838834764831845f;  // 1/sqrt(128)
  u16* Pw = &Ps[w][0];
  const int qrow_l = w * 16 + quad * 4;      // + r

  for (int kt = 0; kt <= qt; ++kt) {
    const int sk0 = (base_s + kt * 64 + shift) & 4095;
    __syncthreads();  // prev iter done with Ks/Vs/Ps
    {
      const u16* ksrc = Kb + ((size_t)(b * 4096 + sk0)) * 512 + kvh * 128;
      #pragma unroll
      for (int u = 0; u < 4; ++u) {
        int idx = tid + u * 256;
        int row = idx >> 4, ch = idx & 15;
        *(uint4*)&Ks[row * 136 + ch * 8] =
            *(const uint4*)(ksrc + (size_t)row * 512 + ch * 8);
      }
      const u16* vsrc = Vt + ((size_t)((b * 4 + kvh) * 128)) * 4096 + sk0;
      #pragma unroll
      for (int u = 0; u < 4; ++u) {
        int idx = tid + u * 256;
        int d = idx >> 3, ch = idx & 7;
        *(uint4*)&Vs[d * 72 + ch * 8] =
            *(const uint4*)(vsrc + (size_t)d * 4096 + ch * 8);
      }
    }
    __syncthreads();

    // ---- S = Q K^T : 16 MFMA ----
    f32x4 sc[4];
    #pragma unroll
    for (int j = 0; j < 4; ++j) sc[j] = (f32x4)(0.0f);
    #pragma unroll
    for (int kk = 0; kk < 4; ++kk) {
      #pragma unroll
      for (int j = 0; j < 4; ++j) {
        bf16x8 bk = *(const bf16x8*)&Ks[(16 * j + col) * 136 + kk * 32 + quad * 8];
        sc[j] = __builtin_amdgcn_mfma_f32_16x16x32_bf16(aq[kk], bk, sc[j], 0, 0, 0);
      }
    }

    // ---- scale + causal mask (only the diagonal tile needs it) ----
    #pragma unroll
    for (int j = 0; j < 4; ++j) {
      #pragma unroll
      for (int r = 0; r < 4; ++r) {
        float s = sc[j][r] * scale;
        if (kt == qt && (16 * j + col) > (qrow_l + r)) s = -1e30f;
        sc[j][r] = s;
      }
    }

    // ---- online softmax; row = quad*4+r, cols across 16-lane group ----
    float corr[4];
    #pragma unroll
    for (int r = 0; r < 4; ++r) {
      float mx = fmaxf(fmaxf(sc[0][r], sc[1][r]), fmaxf(sc[2][r], sc[3][r]));
      mx = fmaxf(mx, __shfl_xor(mx, 1, 64));
      mx = fmaxf(mx, __shfl_xor(mx, 2, 64));
      mx = fmaxf(mx, __shfl_xor(mx, 4, 64));
      mx = fmaxf(mx, __shfl_xor(mx, 8, 64));
      const float mn = fmaxf(mr[r], mx);
      corr[r] = __expf(mr[r] - mn);
      mr[r] = mn;
      float sum = 0.0f;
      #pragma unroll
      for (int j = 0; j < 4; ++j) {
        float p = __expf(sc[j][r] - mn);
        sc[j][r] = p;
        sum += p;
      }
      sum += __shfl_xor(sum, 1, 64);
      sum += __shfl_xor(sum, 2, 64);
      sum += __shfl_xor(sum, 4, 64);
      sum += __shfl_xor(sum, 8, 64);
      lr[r] = lr[r] * corr[r] + sum;
    }

    // ---- P (C-layout) -> LDS (A-layout source) ----
    #pragma unroll
    for (int r = 0; r < 4; ++r)
      #pragma unroll
      for (int j = 0; j < 4; ++j)
        Pw[(quad * 4 + r) * 72 + 16 * j + col] = f2bf(sc[j][r]);

    // rescale O accumulator
    #pragma unroll
    for (int jd = 0; jd < 8; ++jd)
      #pragma unroll
      for (int r = 0; r < 4; ++r) o[jd][r] *= corr[r];

    __syncthreads();  // P visible (and ordered) before PV reads

    // ---- O += P V : 16 MFMA ----
    #pragma unroll
    for (int ks = 0; ks < 2; ++ks) {
      bf16x8 ap = *(const bf16x8*)&Pw[col * 72 + ks * 32 + quad * 8];
      #pragma unroll
      for (int jd = 0; jd < 8; ++jd) {
        bf16x8 bv = *(const bf16x8*)&Vs[(16 * jd + col) * 72 + ks * 32 + quad * 8];
        o[jd] = __builtin_amdgcn_mfma_f32_16x16x32_bf16(ap, bv, o[jd], 0, 0, 0);
      }
    }
  }

  // ---- normalize + store (un-shift: result lands at shifted seq pos) ----
  #pragma unroll
  for (int r = 0; r < 4; ++r) {
    const int qg = qt * 64 + w * 16 + quad * 4 + r;
    const int sq = (base_s + qg + shift) & 4095;
    u16* dst = Ob + ((size_t)(b * 4096 + sq)) * 2048 + h * 128;
    const float inv = 1.0f / lr[r];
    #pragma unroll
    for (int jd = 0; jd < 8; ++jd)
      dst[16 * jd + col] = f2bf(o[jd][r] * inv);
  }
}

// ---------------------------------------------------------------------------
extern "C" void kernel_launch(void* const* d_in, const int* in_sizes, int n_in,
                              void* d_out, int out_size, void* d_ws, size_t ws_size,
                              hipStream_t stream) {
  const float* hs = (const float*)d_in[0];
  const int*   pos = (const int*)d_in[2];
  const float* Wq = (const float*)d_in[3];
  const float* Wk = (const float*)d_in[4];
  const float* Wv = (const float*)d_in[5];
  const float* Wo = (const float*)d_in[6];

  char* ws = (char*)d_ws;
  u16* hsb = (u16*)ws;  ws += (size_t)33554432;   // 8192x2048 bf16
  u16* Wqt = (u16*)ws;  ws += (size_t)8388608;    // 2048x2048 bf16
  u16* Wkt = (u16*)ws;  ws += (size_t)2097152;    // 512x2048
  u16* Wvt = (u16*)ws;  ws += (size_t)2097152;
  u16* Wot = (u16*)ws;  ws += (size_t)8388608;
  u16* Qbf = (u16*)ws;  ws += (size_t)33554432;   // 8192x2048
  u16* Kbf = (u16*)ws;  ws += (size_t)8388608;    // 8192x512
  u16* Vbf = (u16*)ws;  ws += (size_t)8388608;
  u16* Vtt = (u16*)ws;  ws += (size_t)8388608;    // (B,NKV,128,S)
  u16* Obh = (u16*)ws;  ws += (size_t)33554432;   // 8192x2048

  dim3 blk(256);

  cast_bf16_vec<<<16384, blk, 0, stream>>>(hs, hsb);
  wt_cast<<<dim3(32, 32), blk, 0, stream>>>(Wq, Wqt, 2048, 2048);
  wt_cast<<<dim3(8, 32),  blk, 0, stream>>>(Wk, Wkt, 2048, 512);
  wt_cast<<<dim3(8, 32),  blk, 0, stream>>>(Wv, Wvt, 2048, 512);
  wt_cast<<<dim3(32, 32), blk, 0, stream>>>(Wo, Wot, 2048, 2048);

  gemm_bf16<<<dim3(16, 64), blk, 0, stream>>>(hsb, Wqt, nullptr, Qbf, 8192, 2048, 2048);
  gemm_bf16<<<dim3(4, 64),  blk, 0, stream>>>(hsb, Wkt, nullptr, Kbf, 8192, 512, 2048);
  gemm_bf16<<<dim3(4, 64),  blk, 0, stream>>>(hsb, Wvt, nullptr, Vbf, 8192, 512, 2048);

  rope_bf16<<<32768, blk, 0, stream>>>(Qbf, pos, 16);
  rope_bf16<<<8192,  blk, 0, stream>>>(Kbf, pos, 4);
  v_transpose<<<512, blk, 0, stream>>>(Vbf, Vtt);

  attn_mfma<<<2048, blk, 0, stream>>>(Qbf, Kbf, Vtt, Obh);

  gemm_bf16<<<dim3(16, 64), blk, 0, stream>>>(Obh, Wot, (float*)d_out, nullptr, 8192, 2048, 2048);
}

// Round 4
// 568.913 us; speedup vs baseline: 13.6397x; 1.2226x over previous
//
#include <hip/hip_runtime.h>
#include <math.h>

typedef unsigned short u16;
typedef short bf16x8 __attribute__((ext_vector_type(8)));
typedef float f32x4 __attribute__((ext_vector_type(4)));

// Problem constants (B=2, S=4096, H=2048, NH=16, NKV=4, HD=128, g=1024)

__device__ __forceinline__ u16 f2bf(float x) {
  union { float f; unsigned u; } c; c.f = x;
  unsigned r = (c.u + 0x7FFFu + ((c.u >> 16) & 1u)) >> 16;  // RNE
  return (u16)r;
}
__device__ __forceinline__ float bf2f(u16 x) {
  union { unsigned u; float f; } c; c.u = ((unsigned)x) << 16;
  return c.f;
}

// async 16B global -> LDS (wave-uniform LDS base + lane*16)
#define GLD16(gp, lp)                                                   \
  __builtin_amdgcn_global_load_lds(                                     \
      (__attribute__((address_space(1))) void*)(gp),                    \
      (__attribute__((address_space(3))) void*)(lp), 16, 0, 0)

// ---------------------------------------------------------------------------
// fp32 -> bf16 elementwise cast (hidden_states)
// ---------------------------------------------------------------------------
__global__ __launch_bounds__(256) void cast_bf16_vec(
    const float* __restrict__ X, u16* __restrict__ Y) {
  const size_t i = ((size_t)blockIdx.x * 256 + threadIdx.x) * 4;
  float4 v = *(const float4*)(X + i);
  ushort4 o;
  o.x = f2bf(v.x); o.y = f2bf(v.y); o.z = f2bf(v.z); o.w = f2bf(v.w);
  *(ushort4*)(Y + i) = o;
}

// ---------------------------------------------------------------------------
// W (K x N fp32, row-major) -> Wt (N x K bf16, row-major). 64x64 LDS tiles.
// ---------------------------------------------------------------------------
__global__ __launch_bounds__(256) void wt_cast(
    const float* __restrict__ W, u16* __restrict__ Wt, int K, int N) {
  const int bk = blockIdx.y * 64;
  const int bn = blockIdx.x * 64;
  __shared__ float T[64 * 65];
  const int tid = threadIdx.x;
  #pragma unroll
  for (int u = 0; u < 16; ++u) {
    int idx = tid + u * 256;
    int kl = idx >> 6, nl = idx & 63;
    T[kl * 65 + nl] = W[(size_t)(bk + kl) * N + bn + nl];
  }
  __syncthreads();
  #pragma unroll
  for (int u = 0; u < 16; ++u) {
    int idx = tid + u * 256;
    int nl = idx >> 6, kl = idx & 63;
    Wt[(size_t)(bn + nl) * K + bk + kl] = f2bf(T[kl * 65 + nl]);
  }
}

// ---------------------------------------------------------------------------
// bf16 MFMA GEMM (m97 structure): C[M,N] = A[M,K] @ Bt[N,K]^T
// 128x128 tile, BK=32, 256 thr / 4 waves, each wave 64x64 via 4x4 16x16x32.
// Output: fp32 (Cf) or bf16 (Cb) - exactly one non-null.
// ---------------------------------------------------------------------------
__global__ __launch_bounds__(256) void gemm_bf16(
    const u16* __restrict__ A, const u16* __restrict__ Bt,
    float* __restrict__ Cf, u16* __restrict__ Cb, int M, int N, int K) {
  __shared__ u16 As[128 * 32];
  __shared__ u16 Bs[128 * 32];

  const int tid = threadIdx.x;
  const int bm = blockIdx.y * 128;
  const int bn = blockIdx.x * 128;
  const int w = tid >> 6, lane = tid & 63;
  const int col = lane & 15, quad = lane >> 4;
  const int mblk = (w & 1) * 64, nblk = (w >> 1) * 64;

  const int srow = tid >> 2;          // 0..63
  const int sseg = (tid & 3) * 8;     // 8 bf16 = 16 B

  const u16* ag0 = A + (size_t)(bm + srow) * K + sseg;
  const u16* ag1 = A + (size_t)(bm + 64 + srow) * K + sseg;
  const u16* bg0 = Bt + (size_t)(bn + srow) * K + sseg;
  const u16* bg1 = Bt + (size_t)(bn + 64 + srow) * K + sseg;
  u16* al = &As[srow * 32 + sseg];
  u16* bl = &Bs[srow * 32 + sseg];

  f32x4 acc[4][4];
  #pragma unroll
  for (int i = 0; i < 4; ++i)
    #pragma unroll
    for (int j = 0; j < 4; ++j) acc[i][j] = (f32x4)(0.0f);

  for (int k0 = 0; k0 < K; k0 += 32) {
    __syncthreads();
    GLD16(ag0 + k0, al);
    GLD16(ag1 + k0, al + 64 * 32);
    GLD16(bg0 + k0, bl);
    GLD16(bg1 + k0, bl + 64 * 32);
    __syncthreads();

    bf16x8 af[4], bfr[4];
    #pragma unroll
    for (int i = 0; i < 4; ++i)
      af[i] = *(const bf16x8*)&As[(mblk + 16 * i + col) * 32 + quad * 8];
    #pragma unroll
    for (int j = 0; j < 4; ++j)
      bfr[j] = *(const bf16x8*)&Bs[(nblk + 16 * j + col) * 32 + quad * 8];
    #pragma unroll
    for (int i = 0; i < 4; ++i)
      #pragma unroll
      for (int j = 0; j < 4; ++j)
        acc[i][j] = __builtin_amdgcn_mfma_f32_16x16x32_bf16(af[i], bfr[j], acc[i][j], 0, 0, 0);
  }

  // C/D layout: col = lane&15, row = quad*4 + reg  [verified m89/m91]
  #pragma unroll
  for (int i = 0; i < 4; ++i) {
    const int row0 = bm + mblk + 16 * i + quad * 4;
    #pragma unroll
    for (int j = 0; j < 4; ++j) {
      const int cc = bn + nblk + 16 * j + col;
      #pragma unroll
      for (int r = 0; r < 4; ++r) {
        if (Cb) Cb[(size_t)(row0 + r) * N + cc] = f2bf(acc[i][j][r]);
        else    Cf[(size_t)(row0 + r) * N + cc] = acc[i][j][r];
      }
    }
  }
}

// ---------------------------------------------------------------------------
// Fused RoPE on the QKV buffer (8192 rows x 3072 cols bf16).
// head 0..15 = Q (cols h*128, gets 1/sqrt(128) folded in), 16..19 = K
// (cols 2048+(h-16)*128). One thread per (bs, head, d<64).
// ---------------------------------------------------------------------------
__global__ __launch_bounds__(256) void rope_qkv(
    u16* __restrict__ QKV, const int* __restrict__ pos) {
  const unsigned idx = blockIdx.x * 256 + threadIdx.x;
  const int d = idx & 63;
  const unsigned rest = idx >> 6;
  const int hh = rest % 20;
  const unsigned bs = rest / 20;

  const int colbase = (hh < 16) ? hh * 128 : 2048 + (hh - 16) * 128;
  u16* p = QKV + (size_t)bs * 3072 + colbase + d;
  const float x0 = bf2f(p[0]);
  const float x1 = bf2f(p[64]);
  const float t = (float)pos[bs];
  const float inv_freq = __expf((float)d * -0.14391156509676332f);  // ln(1e4)/64
  float s, c;
  __sincosf(t * inv_freq, &s, &c);
  const float sc = (hh < 16) ? 0.08838834764831845f : 1.0f;  // 1/sqrt(128) into Q
  p[0]  = f2bf((x0 * c - x1 * s) * sc);
  p[64] = f2bf((x1 * c + x0 * s) * sc);
}

// ---------------------------------------------------------------------------
// V columns of QKV (offset 2560, stride 3072) -> Vt (B, NKV, 128, S)
// ---------------------------------------------------------------------------
__global__ __launch_bounds__(256) void v_transpose(
    const u16* __restrict__ QKV, u16* __restrict__ Vt) {
  const int bid = blockIdx.x;
  const int st = bid & 63;
  const int kvh = (bid >> 6) & 3;
  const int b = bid >> 8;
  __shared__ u16 T[64 * 136];
  const int tid = threadIdx.x;
  #pragma unroll
  for (int u = 0; u < 4; ++u) {
    int idx = tid + u * 256;
    int sl = idx >> 4, ch = idx & 15;
    *(uint4*)&T[sl * 136 + ch * 8] =
        *(const uint4*)(QKV + ((size_t)(b * 4096 + st * 64 + sl)) * 3072 + 2560 + kvh * 128 + ch * 8);
  }
  __syncthreads();
  #pragma unroll
  for (int u = 0; u < 32; ++u) {
    int idx = tid + u * 256;
    int d = idx >> 6, sl = idx & 63;
    Vt[((size_t)((b * 4 + kvh) * 128 + d)) * 4096 + st * 64 + sl] = T[sl * 136 + d];
  }
}

// ---------------------------------------------------------------------------
// MFMA flash attention, max-free online softmax, S2-shift indexing.
// Block = 256 thr / 4 waves; 64-query tile of one (b,group,head); 64-key tiles.
// Wave w owns q-rows w*16..w*16+15. Q pre-scaled by 1/sqrt(128) in rope.
// LDS 45 KB -> 3 blocks/CU. 2 barriers per K-tile (Ps is wave-private).
// ---------------------------------------------------------------------------
__global__ __launch_bounds__(256) void attn_mfma(
    const u16* __restrict__ QKV, const u16* __restrict__ Vt,
    u16* __restrict__ Ob) {
  __shared__ u16 Ks[64 * 136];    // [key][128d]; also used to stage Q once
  __shared__ u16 Vs[128 * 72];    // [dim][64key]
  __shared__ u16 Ps[4][16 * 72];  // per-wave P [16q][64key]

  const int bid = blockIdx.x;
  const int qt = 15 - (bid & 15);           // heavy tiles first
  const int h  = (bid >> 4) & 15;
  const int gi = (bid >> 8) & 3;
  const int b  = bid >> 10;

  const int tid = threadIdx.x;
  const int w = tid >> 6, lane = tid & 63;
  const int col = lane & 15, quad = lane >> 4;

  const int shift = (h >= 8) ? 512 : 0;
  const int base_s = gi * 1024;
  const int kvh = h >> 2;

  // ---- stage Q tile through Ks, grab persistent A-frags ----
  const int sq0 = (base_s + qt * 64 + shift) & 4095;
  {
    const u16* qsrc = QKV + ((size_t)(b * 4096 + sq0)) * 3072 + h * 128;
    #pragma unroll
    for (int u = 0; u < 4; ++u) {
      int idx = tid + u * 256;
      int row = idx >> 4, ch = idx & 15;
      *(uint4*)&Ks[row * 136 + ch * 8] =
          *(const uint4*)(qsrc + (size_t)row * 3072 + ch * 8);
    }
  }
  __syncthreads();
  bf16x8 aq[4];  // A[m=col][k=quad*8+j] per 32-d chunk
  #pragma unroll
  for (int kk = 0; kk < 4; ++kk)
    aq[kk] = *(const bf16x8*)&Ks[(w * 16 + col) * 136 + kk * 32 + quad * 8];

  f32x4 o[8];
  #pragma unroll
  for (int jd = 0; jd < 8; ++jd) o[jd] = (f32x4)(0.0f);
  float lp[4] = {0.0f, 0.0f, 0.0f, 0.0f};  // per-lane partial denominators

  u16* Pw = &Ps[w][0];
  const int qrow_l = w * 16 + quad * 4;  // + r

  for (int kt = 0; kt <= qt; ++kt) {
    const int sk0 = (base_s + kt * 64 + shift) & 4095;
    __syncthreads();  // all waves done reading Ks/Vs (or aq frags on iter 0)
    {
      const u16* ksrc = QKV + ((size_t)(b * 4096 + sk0)) * 3072 + 2048 + kvh * 128;
      #pragma unroll
      for (int u = 0; u < 4; ++u) {
        int idx = tid + u * 256;
        int row = idx >> 4, ch = idx & 15;
        *(uint4*)&Ks[row * 136 + ch * 8] =
            *(const uint4*)(ksrc + (size_t)row * 3072 + ch * 8);
      }
      const u16* vsrc = Vt + ((size_t)((b * 4 + kvh) * 128)) * 4096 + sk0;
      #pragma unroll
      for (int u = 0; u < 4; ++u) {
        int idx = tid + u * 256;
        int d = idx >> 3, ch = idx & 7;
        *(uint4*)&Vs[d * 72 + ch * 8] =
            *(const uint4*)(vsrc + (size_t)d * 4096 + ch * 8);
      }
    }
    __syncthreads();

    // ---- S = Q K^T : 16 MFMA ----
    f32x4 sc[4];
    #pragma unroll
    for (int j = 0; j < 4; ++j) sc[j] = (f32x4)(0.0f);
    #pragma unroll
    for (int kk = 0; kk < 4; ++kk) {
      #pragma unroll
      for (int j = 0; j < 4; ++j) {
        bf16x8 bk = *(const bf16x8*)&Ks[(16 * j + col) * 136 + kk * 32 + quad * 8];
        sc[j] = __builtin_amdgcn_mfma_f32_16x16x32_bf16(aq[kk], bk, sc[j], 0, 0, 0);
      }
    }

    // ---- exp (no max subtraction; scores bounded), mask, P write, l accum ----
    #pragma unroll
    for (int j = 0; j < 4; ++j) {
      #pragma unroll
      for (int r = 0; r < 4; ++r) {
        float p = __expf(sc[j][r]);
        if (kt == qt && (16 * j + col) > (qrow_l + r)) p = 0.0f;
        lp[r] += p;
        Pw[(quad * 4 + r) * 72 + 16 * j + col] = f2bf(p);
      }
    }
    // Ps is wave-private: no barrier needed (in-wave ds ordering via lgkmcnt)

    // ---- O += P V : 16 MFMA ----
    #pragma unroll
    for (int ks = 0; ks < 2; ++ks) {
      bf16x8 ap = *(const bf16x8*)&Pw[col * 72 + ks * 32 + quad * 8];
      #pragma unroll
      for (int jd = 0; jd < 8; ++jd) {
        bf16x8 bv = *(const bf16x8*)&Vs[(16 * jd + col) * 72 + ks * 32 + quad * 8];
        o[jd] = __builtin_amdgcn_mfma_f32_16x16x32_bf16(ap, bv, o[jd], 0, 0, 0);
      }
    }
  }

  // ---- reduce denominators across the 16 col-lanes (same quad group) ----
  #pragma unroll
  for (int r = 0; r < 4; ++r) {
    lp[r] += __shfl_xor(lp[r], 1, 64);
    lp[r] += __shfl_xor(lp[r], 2, 64);
    lp[r] += __shfl_xor(lp[r], 4, 64);
    lp[r] += __shfl_xor(lp[r], 8, 64);
  }

  // ---- normalize + store (output lands at shifted seq pos = un-shift) ----
  #pragma unroll
  for (int r = 0; r < 4; ++r) {
    const int qg = qt * 64 + w * 16 + quad * 4 + r;
    const int sq = (base_s + qg + shift) & 4095;
    u16* dst = Ob + ((size_t)(b * 4096 + sq)) * 2048 + h * 128;
    const float inv = 1.0f / lp[r];
    #pragma unroll
    for (int jd = 0; jd < 8; ++jd)
      dst[16 * jd + col] = f2bf(o[jd][r] * inv);
  }
}

// ---------------------------------------------------------------------------
extern "C" void kernel_launch(void* const* d_in, const int* in_sizes, int n_in,
                              void* d_out, int out_size, void* d_ws, size_t ws_size,
                              hipStream_t stream) {
  const float* hs = (const float*)d_in[0];
  const int*   pos = (const int*)d_in[2];
  const float* Wq = (const float*)d_in[3];
  const float* Wk = (const float*)d_in[4];
  const float* Wv = (const float*)d_in[5];
  const float* Wo = (const float*)d_in[6];

  char* ws = (char*)d_ws;
  u16* hsb   = (u16*)ws; ws += (size_t)8192 * 2048 * 2;   // 33.5 MB
  u16* Wqkvt = (u16*)ws; ws += (size_t)3072 * 2048 * 2;   // 12.6 MB
  u16* Wot   = (u16*)ws; ws += (size_t)2048 * 2048 * 2;   //  8.4 MB
  u16* QKVb  = (u16*)ws; ws += (size_t)8192 * 3072 * 2;   // 50.3 MB
  u16* Vtt   = (u16*)ws; ws += (size_t)2 * 4 * 128 * 4096 * 2;  // 8.4 MB
  u16* Obh   = (u16*)ws; ws += (size_t)8192 * 2048 * 2;   // 33.5 MB

  dim3 blk(256);

  cast_bf16_vec<<<16384, blk, 0, stream>>>(hs, hsb);
  // Wqkvt rows: 0..2047 = Wq^T, 2048..2559 = Wk^T, 2560..3071 = Wv^T
  wt_cast<<<dim3(32, 32), blk, 0, stream>>>(Wq, Wqkvt, 2048, 2048);
  wt_cast<<<dim3(8, 32),  blk, 0, stream>>>(Wk, Wqkvt + (size_t)2048 * 2048, 2048, 512);
  wt_cast<<<dim3(8, 32),  blk, 0, stream>>>(Wv, Wqkvt + (size_t)2560 * 2048, 2048, 512);
  wt_cast<<<dim3(32, 32), blk, 0, stream>>>(Wo, Wot, 2048, 2048);

  // Fused QKV projection: (8192 x 2048) @ (3072 x 2048)^T -> 8192 x 3072 bf16
  gemm_bf16<<<dim3(24, 64), blk, 0, stream>>>(hsb, Wqkvt, nullptr, QKVb, 8192, 3072, 2048);

  // Fused RoPE (Q scaled by 1/sqrt(128)): 8192 rows x 20 heads x 64 dim-pairs
  rope_qkv<<<40960, blk, 0, stream>>>(QKVb, pos);

  v_transpose<<<512, blk, 0, stream>>>(QKVb, Vtt);

  attn_mfma<<<2048, blk, 0, stream>>>(QKVb, Vtt, Obh);

  gemm_bf16<<<dim3(16, 64), blk, 0, stream>>>(Obh, Wot, (float*)d_out, nullptr, 8192, 2048, 2048);
}